// Round 6
// baseline (129.064 us; speedup 1.0000x reference)
//
#include <hip/hip_runtime.h>
#include <hip/hip_bf16.h>
#include <hip/hip_fp8.h>

#define B_ 8192
#define D_ 256
#define EPS_ 1e-6f
#define MARGIN_ 1.0f
#define NT_ 64                               // 128-row tiles
#define NTILES_ (NT_ * (NT_ + 1) / 2)        // 2080
#define CEPS_ ((float)D_ * EPS_ * EPS_)

typedef float floatx4 __attribute__((ext_vector_type(4)));
typedef int intx4 __attribute__((ext_vector_type(4)));
typedef int intx8 __attribute__((ext_vector_type(8)));

typedef __attribute__((address_space(3))) unsigned int lds_uint_t;
typedef __attribute__((address_space(1))) const unsigned int g_uint_t;

__device__ __forceinline__ void g2l16(const unsigned char* g, unsigned char* l) {
    __builtin_amdgcn_global_load_lds((g_uint_t*)g, (lds_uint_t*)l, 16, 0, 0);
}

// ws layout: [0, 2MB) fp8 matrix; float region after 4 MB (offsets in floats)
#define XBF_BYTES (B_ * D_ * 2)
#define OFF_P      0
#define OFF_Q      8192
#define OFF_TP0    16384
#define OFF_TP1    81920
#define OFF_PPP    147456
#define OFF_QQP    147968
#define OFF_CP     148480
#define OFF_PMINP  148736
#define OFF_QMINP  148992
#define OFF_ACC    149248
#define OFF_DONE   149250

__device__ __forceinline__ int trif(int t) { return (t * (129 - t)) / 2; }
__device__ __forceinline__ int decode_ti(int t) {
    int ti = (int)((129.0f - sqrtf(fmaxf(16641.0f - 8.0f * (float)t, 0.0f))) * 0.5f);
    ti = max(0, min(63, ti));
    while (trif(ti + 1) <= t) ++ti;
    while (trif(ti) > t) --ti;
    return ti;
}

struct FinalShared {
    floatx4 s0q[4][64], s1q[4][64], ssq[4][64];
    double tP0[64], tP1[64], tQ0[64], tQ1[64], tC0[64];
    float g2s;
};

// ---------------- prep: 256 blocks x 32 rows; p/q, col-sums, fp8 cast ----------------
__global__ __launch_bounds__(256) void prep_kernel(
    const float* __restrict__ x, const int* __restrict__ label,
    unsigned char* __restrict__ xq, float* __restrict__ fws) {
    float* p = fws + OFF_P;   float* q = fws + OFF_Q;
    float* Tp0 = fws + OFF_TP0; float* Tp1 = fws + OFF_TP1;
    float* PpP = fws + OFF_PPP; float* QqP = fws + OFF_QQP;
    float* CpP = fws + OFF_CP;
    float* pminP = fws + OFF_PMINP; float* qminP = fws + OFF_QMINP;

    __shared__ int lab_s[32];
    __shared__ float spl[32], sql[32];
    __shared__ float colbuf0[4][256], colbuf1[4][256];

    const int blk = blockIdx.x;
    const int r0 = blk * 32;
    const int tid = threadIdx.x, w = tid >> 6, lane = tid & 63;

    if (tid < 32) lab_s[tid] = label[r0 + tid];
    __syncthreads();

    floatx4 t0 = (floatx4)0.0f, t1 = (floatx4)0.0f;
    #pragma unroll
    for (int i = 0; i < 8; ++i) {
        const int rloc = w * 8 + i;
        const int row = r0 + rloc;
        const floatx4 v = *(const floatx4*)(x + (size_t)row * D_ + lane * 4);
        float sq = v[0]*v[0] + v[1]*v[1] + v[2]*v[2] + v[3]*v[3];
        float rs = v[0] + v[1] + v[2] + v[3];
        #pragma unroll
        for (int off = 32; off; off >>= 1) {
            sq += __shfl_down(sq, off);
            rs += __shfl_down(rs, off);
        }
        if (lane == 0) {
            const float pv = sq + 2.0f * EPS_ * rs;
            const float qv = sq - 2.0f * EPS_ * rs;
            p[row] = pv; q[row] = qv; spl[rloc] = pv; sql[rloc] = qv;
        }
        if (lab_s[rloc]) t1 += v; else t0 += v;   // wave-uniform branch
        __hip_fp8_e4m3 c0(v[0]), c1(v[1]), c2(v[2]), c3(v[3]);
        const unsigned int u = (unsigned int)c0.__x | ((unsigned int)c1.__x << 8)
                             | ((unsigned int)c2.__x << 16) | ((unsigned int)c3.__x << 24);
        *(unsigned int*)(xq + (size_t)row * D_ + lane * 4) = u;
    }
    *(floatx4*)&colbuf0[w][lane * 4] = t0;
    *(floatx4*)&colbuf1[w][lane * 4] = t1;
    __syncthreads();

    {
        const int c = tid;
        Tp0[blk * 256 + c] = colbuf0[0][c] + colbuf0[1][c] + colbuf0[2][c] + colbuf0[3][c];
        Tp1[blk * 256 + c] = colbuf1[0][c] + colbuf1[1][c] + colbuf1[2][c] + colbuf1[3][c];
    }
    if (tid < 64) {
        const bool va = tid < 32;
        const float pv = va ? spl[tid & 31] : 0.0f;
        const float qv = va ? sql[tid & 31] : 0.0f;
        const int lb = va ? lab_s[tid & 31] : 0;
        float p0 = (va && !lb) ? pv : 0.0f, p1 = (va && lb) ? pv : 0.0f;
        float q0 = (va && !lb) ? qv : 0.0f, q1 = (va && lb) ? qv : 0.0f;
        float c0 = (va && !lb) ? 1.0f : 0.0f;
        float pm = va ? pv : 1e30f, qm = va ? qv : 1e30f;
        #pragma unroll
        for (int off = 32; off; off >>= 1) {
            p0 += __shfl_down(p0, off); p1 += __shfl_down(p1, off);
            q0 += __shfl_down(q0, off); q1 += __shfl_down(q1, off);
            c0 += __shfl_down(c0, off);
            pm = fminf(pm, __shfl_down(pm, off));
            qm = fminf(qm, __shfl_down(qm, off));
        }
        if (tid == 0) {
            PpP[blk * 2 + 0] = p0; PpP[blk * 2 + 1] = p1;
            QqP[blk * 2 + 0] = q0; QqP[blk * 2 + 1] = q1;
            CpP[blk] = c0; pminP[blk] = pm; qminP[blk] = qm;
            if (blk == 0) {
                fws[OFF_ACC] = 0.0f;
                ((unsigned*)(fws + OFF_DONE))[0] = 0u;
            }
        }
    }
}

// ---------------- tile: MX-fp8 gram, 32 KB LDS, 3 blocks/CU, fused finalize ----------------
__global__ __launch_bounds__(256, 3) void tile_kernel(
    const unsigned char* __restrict__ xq, const float* __restrict__ x,
    const int* __restrict__ label, float* __restrict__ fws,
    float* __restrict__ out) {
    const float* p = fws + OFF_P;  const float* q = fws + OFF_Q;
    const float* pminP = fws + OFF_PMINP; const float* qminP = fws + OFF_QMINP;
    float* acc = fws + OFF_ACC;
    unsigned* done = (unsigned*)(fws + OFF_DONE);

    const int ti = decode_ti(blockIdx.x);
    const int tj = ti + (blockIdx.x - trif(ti));
    const int i0 = ti * 128, j0 = tj * 128;

    __shared__ union {
        struct { __align__(16) unsigned char A[128 * 128], B[128 * 128]; } m;  // 32 KB
        FinalShared f;
    } sh;
    __shared__ int last_s;

    const int tid = threadIdx.x, wave = tid >> 6, lane = tid & 63;
    const int quad = lane >> 4, r = lane & 15, r7 = r & 7;
    const int wm = wave >> 1, wn = wave & 1;

    // staging: instr i covers rows wave*32+i*8 .. +7; lane: row rL8, phys chunk cL,
    // logical chunk cL^rL8 (key = row&7 since i*8 ≡ 0 mod 8)
    const int rL8 = lane >> 3, cL = lane & 7;
    const size_t lane_src = (size_t)rL8 * D_ + (size_t)((cL ^ rL8) * 16);
    const unsigned char* gA0 = xq + (size_t)(i0 + wave * 32) * D_ + lane_src;
    const unsigned char* gB0 = xq + (size_t)(j0 + wave * 32) * D_ + lane_src;

    // fragment addresses: row stride 128 B; quad q needs logical chunks 2q, 2q+1
    int rbA[4], rbB[4];
    #pragma unroll
    for (int mt = 0; mt < 4; ++mt) rbA[mt] = (wm * 64 + mt * 16 + r) * 128;
    #pragma unroll
    for (int nt = 0; nt < 4; ++nt) rbB[nt] = (wn * 64 + nt * 16 + r) * 128;
    const int co0 = ((2 * quad) ^ r7) * 16;
    const int co1 = ((2 * quad + 1) ^ r7) * 16;

    floatx4 accv[16];
    #pragma unroll
    for (int t = 0; t < 16; ++t) accv[t] = (floatx4)0.0f;

    #pragma unroll
    for (int kh = 0; kh < 2; ++kh) {
        if (kh) __syncthreads();           // all waves done reading half-0 LDS
        #pragma unroll
        for (int i = 0; i < 4; ++i) {
            g2l16(gA0 + (size_t)i * 8 * D_ + kh * 128, &sh.m.A[(wave * 32 + i * 8) * 128]);
            g2l16(gB0 + (size_t)i * 8 * D_ + kh * 128, &sh.m.B[(wave * 32 + i * 8) * 128]);
        }
        __syncthreads();                   // drain this half's g2l16

        intx8 bfr[4];
        #pragma unroll
        for (int nt = 0; nt < 4; ++nt) {
            const intx4 lo = *(const intx4*)&sh.m.B[rbB[nt] + co0];
            const intx4 hi = *(const intx4*)&sh.m.B[rbB[nt] + co1];
            bfr[nt] = __builtin_shufflevector(lo, hi, 0, 1, 2, 3, 4, 5, 6, 7);
        }
        #pragma unroll
        for (int mt = 0; mt < 4; ++mt) {
            const intx4 lo = *(const intx4*)&sh.m.A[rbA[mt] + co0];
            const intx4 hi = *(const intx4*)&sh.m.A[rbA[mt] + co1];
            const intx8 af = __builtin_shufflevector(lo, hi, 0, 1, 2, 3, 4, 5, 6, 7);
            #pragma unroll
            for (int nt = 0; nt < 4; ++nt)
                accv[mt * 4 + nt] = __builtin_amdgcn_mfma_scale_f32_16x16x128_f8f6f4(
                    af, bfr[nt], accv[mt * 4 + nt], 0, 0, 0, 0x7F, 0, 0x7F);
        }
    }

    // ---- epilogue ----
    if (ti != tj) {
        float m = -1e30f;
        #pragma unroll
        for (int t = 0; t < 16; ++t)
            m = fmaxf(m, fmaxf(fmaxf(accv[t][0], accv[t][1]), fmaxf(accv[t][2], accv[t][3])));
        const float pmn = fminf(fminf(pminP[4 * ti], pminP[4 * ti + 1]),
                                fminf(pminP[4 * ti + 2], pminP[4 * ti + 3]));
        const float qmn = fminf(fminf(qminP[4 * tj], qminP[4 * tj + 1]),
                                fminf(qminP[4 * tj + 2], qminP[4 * tj + 3]));
        const float thr = (pmn + qmn + CEPS_ - 1.0f) * 0.5f - 16.0f;  // 16 = fp8 slack
        if (__any(m > thr)) {
            // exact slow path from fp32 x (expected never taken)
            float s = 0.0f;
            #pragma unroll
            for (int mt = 0; mt < 4; ++mt)
                #pragma unroll
                for (int nt = 0; nt < 4; ++nt)
                    #pragma unroll
                    for (int reg = 0; reg < 4; ++reg) {
                        const int gi = i0 + wm * 64 + mt * 16 + quad * 4 + reg;
                        const int gj = j0 + wn * 64 + nt * 16 + r;
                        const float sq8 = p[gi] + q[gj] + CEPS_ - 2.0f * accv[mt * 4 + nt][reg];
                        if (sq8 < 33.0f && label[gi] != label[gj]) {
                            const float* xi = x + (size_t)gi * D_;
                            const float* xj = x + (size_t)gj * D_;
                            float sq = 0.0f;
                            for (int k = 0; k < D_; ++k) {
                                const float df = xi[k] - xj[k] + EPS_;
                                sq += df * df;
                            }
                            if (sq < 1.0f) {
                                const float d = sqrtf(fmaxf(sq, 1e-12f));
                                const float h = MARGIN_ - d;
                                s += h * h;
                            }
                        }
                    }
            #pragma unroll
            for (int off = 32; off; off >>= 1) s += __shfl_down(s, off);
            if (lane == 0) atomicAdd(acc, s);
        }
    } else {
        // diagonal: exact per-pair, strict upper triangle
        float s = 0.0f;
        #pragma unroll
        for (int mt = 0; mt < 4; ++mt)
            #pragma unroll
            for (int nt = 0; nt < 4; ++nt)
                #pragma unroll
                for (int reg = 0; reg < 4; ++reg) {
                    const int il = wm * 64 + mt * 16 + quad * 4 + reg;
                    const int jl = wn * 64 + nt * 16 + r;
                    if (il < jl) {
                        const int gi = i0 + il, gj = j0 + jl;
                        const float sq = p[gi] + q[gj] + CEPS_ - 2.0f * accv[mt * 4 + nt][reg];
                        const float d = sqrtf(fmaxf(sq, 1e-12f));
                        float v;
                        if (label[gi] == label[gj]) v = d * d;
                        else { const float h = fmaxf(MARGIN_ - d, 0.0f); v = h * h; }
                        s += v;
                    }
                }
        #pragma unroll
        for (int off = 32; off; off >>= 1) s += __shfl_down(s, off);
        if (lane == 0) atomicAdd(acc, s);
    }

    // ---- completion: last block runs the analytic finalize ----
    __syncthreads();   // drains this block's atomicAdds (vmcnt0 before barrier)
    if (tid == 0) {
        __threadfence();
        last_s = (atomicAdd(done, 1u) == NTILES_ - 1u);
    }
    __syncthreads();
    if (!last_s) return;

    {
        const float* Tp0 = fws + OFF_TP0; const float* Tp1 = fws + OFF_TP1;
        const float* PpP = fws + OFF_PPP; const float* QqP = fws + OFF_QQP;
        const float* CpP = fws + OFF_CP;
        FinalShared& F = sh.f;
        const int quad64 = tid & 63, tq = tid >> 6;

        floatx4 a0 = (floatx4)0.0f, a1 = (floatx4)0.0f, as = (floatx4)0.0f;
        for (int t = tq; t < 64; t += 4) {
            floatx4 T0 = (floatx4)0.0f, T1 = (floatx4)0.0f;
            #pragma unroll
            for (int b4 = 0; b4 < 4; ++b4) {
                const int blk = 4 * t + b4;
                T0 += *(const floatx4*)&Tp0[blk * 256 + quad64 * 4];
                T1 += *(const floatx4*)&Tp1[blk * 256 + quad64 * 4];
            }
            a0 += T0; as += T0 * T0;
            a1 += T1; as += T1 * T1;
        }
        F.s0q[tq][quad64] = a0; F.s1q[tq][quad64] = a1; F.ssq[tq][quad64] = as;

        if (tid >= 64 && tid < 128) {
            const int t = tid - 64;
            double P0 = 0, P1 = 0, Q0 = 0, Q1 = 0, C0 = 0;
            #pragma unroll
            for (int b4 = 0; b4 < 4; ++b4) {
                const int blk = 4 * t + b4;
                P0 += PpP[blk * 2]; P1 += PpP[blk * 2 + 1];
                Q0 += QqP[blk * 2]; Q1 += QqP[blk * 2 + 1];
                C0 += CpP[blk];
            }
            F.tP0[t] = P0; F.tP1[t] = P1; F.tQ0[t] = Q0; F.tQ1[t] = Q1; F.tC0[t] = C0;
        }
        __syncthreads();

        if (tid < 64) {
            const floatx4 S0 = F.s0q[0][tid] + F.s0q[1][tid] + F.s0q[2][tid] + F.s0q[3][tid];
            const floatx4 S1 = F.s1q[0][tid] + F.s1q[1][tid] + F.s1q[2][tid] + F.s1q[3][tid];
            const floatx4 SS = F.ssq[0][tid] + F.ssq[1][tid] + F.ssq[2][tid] + F.ssq[3][tid];
            float c = S0[0]*S0[0] + S0[1]*S0[1] + S0[2]*S0[2] + S0[3]*S0[3]
                    + S1[0]*S1[0] + S1[1]*S1[1] + S1[2]*S1[2] + S1[3]*S1[3]
                    - (SS[0] + SS[1] + SS[2] + SS[3]);
            #pragma unroll
            for (int off = 32; off; off >>= 1) c += __shfl_down(c, off);
            if (tid == 0) F.g2s = c;
        }
        __syncthreads();

        if (tid == 0) {
            double cross = -(double)F.g2s;
            double sufC0 = 0, sufC1 = 0, sufQ0 = 0, sufQ1 = 0;
            for (int t = 63; t >= 0; --t) {
                const double C0 = F.tC0[t], C1 = 128.0 - C0;
                cross += F.tP0[t] * sufC0 + F.tP1[t] * sufC1 + sufQ0 * C0 + sufQ1 * C1
                       + (double)CEPS_ * (C0 * sufC0 + C1 * sufC1);
                sufC0 += C0; sufC1 += C1; sufQ0 += F.tQ0[t]; sufQ1 += F.tQ1[t];
            }
            const double total = cross + (double)atomicAdd(acc, 0.0f);
            const double cnt = (double)B_ * (double)(B_ - 1) / 2.0 + 1e-6;
            out[0] = (float)(total / cnt);
        }
    }
}

extern "C" void kernel_launch(void* const* d_in, const int* in_sizes, int n_in,
                              void* d_out, int out_size, void* d_ws, size_t ws_size,
                              hipStream_t stream) {
    const float* x = (const float*)d_in[0];
    const int* label = (const int*)d_in[1];
    float* out = (float*)d_out;

    char* ws = (char*)d_ws;
    unsigned char* xq = (unsigned char*)ws;
    float* fws = (float*)(ws + XBF_BYTES);

    prep_kernel<<<B_ / 32, 256, 0, stream>>>(x, label, xq, fws);
    tile_kernel<<<NTILES_, 256, 0, stream>>>(xq, x, label, fws, out);
}

// Round 7
// 105.262 us; speedup vs baseline: 1.2261x; 1.2261x over previous
//
#include <hip/hip_runtime.h>
#include <hip/hip_bf16.h>
#include <hip/hip_fp8.h>

#define B_ 8192
#define D_ 256
#define EPS_ 1e-6f
#define MARGIN_ 1.0f
#define NT_ 64                               // 128-row i-tiles
#define NJT_ 128                             // 64-row j-tiles
#define NBLK_ 4160                           // sum over ti of (128 - 2*ti)
#define CEPS_ ((float)D_ * EPS_ * EPS_)

typedef float floatx4 __attribute__((ext_vector_type(4)));

typedef __attribute__((address_space(3))) unsigned int lds_uint_t;
typedef __attribute__((address_space(1))) const unsigned int g_uint_t;

__device__ __forceinline__ void g2l16(const unsigned char* g, unsigned char* l) {
    __builtin_amdgcn_global_load_lds((g_uint_t*)g, (lds_uint_t*)l, 16, 0, 0);
}

// ws layout: [0, 2MB) fp8 matrix; float region after 4 MB (offsets in floats)
#define XBF_BYTES (B_ * D_ * 2)
#define OFF_P      0
#define OFF_Q      8192
#define OFF_TP0    16384
#define OFF_TP1    81920
#define OFF_PPP    147456
#define OFF_QQP    147968
#define OFF_CP     148480
#define OFF_PMINP  148736
#define OFF_QMINP  148992
#define OFF_ACC    149248

// cum(ti) = ti*(129-ti) blocks before i-tile row ti
__device__ __forceinline__ int cumf(int t) { return t * (129 - t); }

// ---------------- prep: 256 blocks x 32 rows; p/q, col-sums, fp8 cast ----------------
__global__ __launch_bounds__(256) void prep_kernel(
    const float* __restrict__ x, const int* __restrict__ label,
    unsigned char* __restrict__ xq, float* __restrict__ fws) {
    float* p = fws + OFF_P;   float* q = fws + OFF_Q;
    float* Tp0 = fws + OFF_TP0; float* Tp1 = fws + OFF_TP1;
    float* PpP = fws + OFF_PPP; float* QqP = fws + OFF_QQP;
    float* CpP = fws + OFF_CP;
    float* pminP = fws + OFF_PMINP; float* qminP = fws + OFF_QMINP;

    __shared__ int lab_s[32];
    __shared__ float spl[32], sql[32];
    __shared__ float colbuf0[4][256], colbuf1[4][256];

    const int blk = blockIdx.x;
    const int r0 = blk * 32;
    const int tid = threadIdx.x, w = tid >> 6, lane = tid & 63;

    if (tid < 32) lab_s[tid] = label[r0 + tid];
    __syncthreads();

    floatx4 t0 = (floatx4)0.0f, t1 = (floatx4)0.0f;
    #pragma unroll
    for (int i = 0; i < 8; ++i) {
        const int rloc = w * 8 + i;
        const int row = r0 + rloc;
        const floatx4 v = *(const floatx4*)(x + (size_t)row * D_ + lane * 4);
        float sq = v[0]*v[0] + v[1]*v[1] + v[2]*v[2] + v[3]*v[3];
        float rs = v[0] + v[1] + v[2] + v[3];
        #pragma unroll
        for (int off = 32; off; off >>= 1) {
            sq += __shfl_down(sq, off);
            rs += __shfl_down(rs, off);
        }
        if (lane == 0) {
            const float pv = sq + 2.0f * EPS_ * rs;
            const float qv = sq - 2.0f * EPS_ * rs;
            p[row] = pv; q[row] = qv; spl[rloc] = pv; sql[rloc] = qv;
        }
        if (lab_s[rloc]) t1 += v; else t0 += v;   // wave-uniform branch
        __hip_fp8_e4m3 c0(v[0]), c1(v[1]), c2(v[2]), c3(v[3]);
        const unsigned int u = (unsigned int)c0.__x | ((unsigned int)c1.__x << 8)
                             | ((unsigned int)c2.__x << 16) | ((unsigned int)c3.__x << 24);
        *(unsigned int*)(xq + (size_t)row * D_ + lane * 4) = u;
    }
    *(floatx4*)&colbuf0[w][lane * 4] = t0;
    *(floatx4*)&colbuf1[w][lane * 4] = t1;
    __syncthreads();

    {
        const int c = tid;
        Tp0[blk * 256 + c] = colbuf0[0][c] + colbuf0[1][c] + colbuf0[2][c] + colbuf0[3][c];
        Tp1[blk * 256 + c] = colbuf1[0][c] + colbuf1[1][c] + colbuf1[2][c] + colbuf1[3][c];
    }
    if (tid < 64) {
        const bool va = tid < 32;
        const float pv = va ? spl[tid & 31] : 0.0f;
        const float qv = va ? sql[tid & 31] : 0.0f;
        const int lb = va ? lab_s[tid & 31] : 0;
        float p0 = (va && !lb) ? pv : 0.0f, p1 = (va && lb) ? pv : 0.0f;
        float q0 = (va && !lb) ? qv : 0.0f, q1 = (va && lb) ? qv : 0.0f;
        float c0 = (va && !lb) ? 1.0f : 0.0f;
        float pm = va ? pv : 1e30f, qm = va ? qv : 1e30f;
        #pragma unroll
        for (int off = 32; off; off >>= 1) {
            p0 += __shfl_down(p0, off); p1 += __shfl_down(p1, off);
            q0 += __shfl_down(q0, off); q1 += __shfl_down(q1, off);
            c0 += __shfl_down(c0, off);
            pm = fminf(pm, __shfl_down(pm, off));
            qm = fminf(qm, __shfl_down(qm, off));
        }
        if (tid == 0) {
            PpP[blk * 2 + 0] = p0; PpP[blk * 2 + 1] = p1;
            QqP[blk * 2 + 0] = q0; QqP[blk * 2 + 1] = q1;
            CpP[blk] = c0; pminP[blk] = pm; qminP[blk] = qm;
            if (blk == 0) fws[OFF_ACC] = 0.0f;
        }
    }
}

// ---------------- tile: fp8 gram, 128x64 tile, 512 threads, 3 blocks/CU ----------------
__global__ __launch_bounds__(512, 6) void tile_kernel(
    const unsigned char* __restrict__ xq, const float* __restrict__ x,
    const int* __restrict__ label, const float* __restrict__ fws,
    float* __restrict__ acc) {
    const float* p = fws + OFF_P;  const float* q = fws + OFF_Q;
    const float* pminP = fws + OFF_PMINP; const float* qminP = fws + OFF_QMINP;

    // decode (ti, jj): jj in [2*ti, 128)
    const int b = blockIdx.x;
    int ti = (int)((129.0f - sqrtf((float)(16641 - 4 * b))) * 0.5f);
    ti = max(0, min(63, ti));
    while (cumf(ti + 1) <= b) ++ti;
    while (cumf(ti) > b) --ti;
    const int jj = 2 * ti + (b - cumf(ti));
    const int i0 = ti * 128, j0 = jj * 64;
    const bool overlap = (j0 < i0 + 128);   // jj == 2ti or 2ti+1

    __shared__ __align__(16) unsigned char As[128 * 256];  // 32 KB
    __shared__ __align__(16) unsigned char Bs[64 * 256];   // 16 KB
    __shared__ float wsum[8];

    const int tid = threadIdx.x, wave = tid >> 6, lane = tid & 63;
    const int quad = lane >> 4, r = lane & 15, r7 = r & 7;
    const int wm = wave >> 1, wn = wave & 1;   // 4x2 wave grid, 32x32 each

    // staging: per g2l16 instr a wave covers 4 rows x 256 B; lane: row rL4, chunk c16
    const int rL4 = lane >> 4, c16 = lane & 15;
    {
        #pragma unroll
        for (int i = 0; i < 4; ++i) {
            const int row = wave * 16 + i * 4 + rL4;
            const int src = row * 256 + ((c16 ^ (row & 7)) * 16);
            g2l16(xq + (size_t)i0 * 256 + src, &As[(wave * 16 + i * 4) * 256]);
        }
        #pragma unroll
        for (int i = 0; i < 2; ++i) {
            const int row = wave * 8 + i * 4 + rL4;
            const int src = row * 256 + ((c16 ^ (row & 7)) * 16);
            g2l16(xq + (size_t)j0 * 256 + src, &Bs[(wave * 8 + i * 4) * 256]);
        }
    }

    // fragment bases (row stride 256 B); logical chunk lc stored at physical lc^(row&7)
    int rbA[2], rbB[2];
    #pragma unroll
    for (int mt = 0; mt < 2; ++mt) rbA[mt] = (wm * 32 + mt * 16 + r) * 256;
    #pragma unroll
    for (int nt = 0; nt < 2; ++nt) rbB[nt] = (wn * 32 + nt * 16 + r) * 256;
    const int q8 = (quad & 1) * 8, qh = quad >> 1;

    floatx4 accv[4];
    #pragma unroll
    for (int t = 0; t < 4; ++t) accv[t] = (floatx4)0.0f;

    __syncthreads();   // single drain: all 48 KB staged

    #pragma unroll
    for (int kb = 0; kb < 8; ++kb) {
        const int pcb = (((kb * 2 + qh) ^ r7) * 16) + q8;
        long av[2], bv[2];
        #pragma unroll
        for (int mt = 0; mt < 2; ++mt) av[mt] = *(const long*)(As + rbA[mt] + pcb);
        #pragma unroll
        for (int nt = 0; nt < 2; ++nt) bv[nt] = *(const long*)(Bs + rbB[nt] + pcb);
        #pragma unroll
        for (int mt = 0; mt < 2; ++mt)
            #pragma unroll
            for (int nt = 0; nt < 2; ++nt)
                accv[mt * 2 + nt] = __builtin_amdgcn_mfma_f32_16x16x32_fp8_fp8(
                    av[mt], bv[nt], accv[mt * 2 + nt], 0, 0, 0);
    }

    // ---- epilogue ----
    float s = 0.0f;
    if (!overlap) {
        float m = -1e30f;
        #pragma unroll
        for (int t = 0; t < 4; ++t)
            m = fmaxf(m, fmaxf(fmaxf(accv[t][0], accv[t][1]), fmaxf(accv[t][2], accv[t][3])));
        const float pmn = fminf(fminf(pminP[4 * ti], pminP[4 * ti + 1]),
                                fminf(pminP[4 * ti + 2], pminP[4 * ti + 3]));
        const float qmn = fminf(qminP[2 * jj], qminP[2 * jj + 1]);
        const float thr = (pmn + qmn + CEPS_ - 1.0f) * 0.5f - 16.0f;  // 16 = fp8 slack
        if (__any(m > thr)) {
            // exact slow path from fp32 x (expected never taken)
            #pragma unroll
            for (int mt = 0; mt < 2; ++mt)
                #pragma unroll
                for (int nt = 0; nt < 2; ++nt)
                    #pragma unroll
                    for (int reg = 0; reg < 4; ++reg) {
                        const int gi = i0 + wm * 32 + mt * 16 + quad * 4 + reg;
                        const int gj = j0 + wn * 32 + nt * 16 + r;
                        const float sq8 = p[gi] + q[gj] + CEPS_ - 2.0f * accv[mt * 2 + nt][reg];
                        if (sq8 < 33.0f && label[gi] != label[gj]) {
                            const float* xi = x + (size_t)gi * D_;
                            const float* xj = x + (size_t)gj * D_;
                            float sq = 0.0f;
                            for (int k = 0; k < D_; ++k) {
                                const float df = xi[k] - xj[k] + EPS_;
                                sq += df * df;
                            }
                            if (sq < 1.0f) {
                                const float d = sqrtf(fmaxf(sq, 1e-12f));
                                const float h = MARGIN_ - d;
                                s += h * h;
                            }
                        }
                    }
        }
    } else {
        // overlap tiles: exact per-pair, strict upper triangle via gi < gj
        #pragma unroll
        for (int mt = 0; mt < 2; ++mt)
            #pragma unroll
            for (int nt = 0; nt < 2; ++nt)
                #pragma unroll
                for (int reg = 0; reg < 4; ++reg) {
                    const int gi = i0 + wm * 32 + mt * 16 + quad * 4 + reg;
                    const int gj = j0 + wn * 32 + nt * 16 + r;
                    if (gi < gj) {
                        const float sq = p[gi] + q[gj] + CEPS_ - 2.0f * accv[mt * 2 + nt][reg];
                        const float d = sqrtf(fmaxf(sq, 1e-12f));
                        float v;
                        if (label[gi] == label[gj]) v = d * d;
                        else { const float h = fmaxf(MARGIN_ - d, 0.0f); v = h * h; }
                        s += v;
                    }
                }
    }
    #pragma unroll
    for (int off = 32; off; off >>= 1) s += __shfl_down(s, off);
    if (lane == 0) wsum[wave] = s;
    __syncthreads();
    if (tid == 0) {
        const float t = (wsum[0] + wsum[1]) + (wsum[2] + wsum[3])
                      + (wsum[4] + wsum[5]) + (wsum[6] + wsum[7]);
        if (t != 0.0f || overlap) atomicAdd(acc, t);
    }
}

// ---------------- finalize: parallel analytic cross-tile same-label sum ----------------
__global__ __launch_bounds__(256) void finalize_kernel(
    const float* __restrict__ fws, float* __restrict__ out) {
    const float* Tp0 = fws + OFF_TP0; const float* Tp1 = fws + OFF_TP1;
    const float* PpP = fws + OFF_PPP; const float* QqP = fws + OFF_QQP;
    const float* CpP = fws + OFF_CP;
    const float* acc = fws + OFF_ACC;

    __shared__ floatx4 s0q[4][64], s1q[4][64], ssq[4][64];
    __shared__ float g2s;
    __shared__ double tP0[64], tP1[64], tQ0[64], tQ1[64], tC0[64];

    const int tid = threadIdx.x;
    const int quad = tid & 63, tq = tid >> 6;

    floatx4 a0 = (floatx4)0.0f, a1 = (floatx4)0.0f, as = (floatx4)0.0f;
    for (int t = tq; t < 64; t += 4) {
        floatx4 T0 = (floatx4)0.0f, T1 = (floatx4)0.0f;
        #pragma unroll
        for (int b4 = 0; b4 < 4; ++b4) {
            const int blk = 4 * t + b4;
            T0 += *(const floatx4*)&Tp0[blk * 256 + quad * 4];
            T1 += *(const floatx4*)&Tp1[blk * 256 + quad * 4];
        }
        a0 += T0; as += T0 * T0;
        a1 += T1; as += T1 * T1;
    }
    s0q[tq][quad] = a0; s1q[tq][quad] = a1; ssq[tq][quad] = as;

    if (tid >= 64 && tid < 128) {
        const int t = tid - 64;
        double P0 = 0, P1 = 0, Q0 = 0, Q1 = 0, C0 = 0;
        #pragma unroll
        for (int b4 = 0; b4 < 4; ++b4) {
            const int blk = 4 * t + b4;
            P0 += PpP[blk * 2]; P1 += PpP[blk * 2 + 1];
            Q0 += QqP[blk * 2]; Q1 += QqP[blk * 2 + 1];
            C0 += CpP[blk];
        }
        tP0[t] = P0; tP1[t] = P1; tQ0[t] = Q0; tQ1[t] = Q1; tC0[t] = C0;
    }
    __syncthreads();

    if (tid < 64) {
        const floatx4 S0 = s0q[0][tid] + s0q[1][tid] + s0q[2][tid] + s0q[3][tid];
        const floatx4 S1 = s1q[0][tid] + s1q[1][tid] + s1q[2][tid] + s1q[3][tid];
        const floatx4 SS = ssq[0][tid] + ssq[1][tid] + ssq[2][tid] + ssq[3][tid];
        float c = S0[0]*S0[0] + S0[1]*S0[1] + S0[2]*S0[2] + S0[3]*S0[3]
                + S1[0]*S1[0] + S1[1]*S1[1] + S1[2]*S1[2] + S1[3]*S1[3]
                - (SS[0] + SS[1] + SS[2] + SS[3]);
        #pragma unroll
        for (int off = 32; off; off >>= 1) c += __shfl_down(c, off);
        if (tid == 0) g2s = c;
    }
    __syncthreads();

    if (tid == 0) {
        double cross = -(double)g2s;
        double sufC0 = 0, sufC1 = 0, sufQ0 = 0, sufQ1 = 0;
        for (int t = 63; t >= 0; --t) {
            const double C0 = tC0[t], C1 = 128.0 - C0;
            cross += tP0[t] * sufC0 + tP1[t] * sufC1 + sufQ0 * C0 + sufQ1 * C1
                   + (double)CEPS_ * (C0 * sufC0 + C1 * sufC1);
            sufC0 += C0; sufC1 += C1; sufQ0 += tQ0[t]; sufQ1 += tQ1[t];
        }
        const double total = cross + (double)acc[0];
        const double cnt = (double)B_ * (double)(B_ - 1) / 2.0 + 1e-6;
        out[0] = (float)(total / cnt);
    }
}

extern "C" void kernel_launch(void* const* d_in, const int* in_sizes, int n_in,
                              void* d_out, int out_size, void* d_ws, size_t ws_size,
                              hipStream_t stream) {
    const float* x = (const float*)d_in[0];
    const int* label = (const int*)d_in[1];
    float* out = (float*)d_out;

    char* ws = (char*)d_ws;
    unsigned char* xq = (unsigned char*)ws;
    float* fws = (float*)(ws + XBF_BYTES);
    float* acc = fws + OFF_ACC;

    prep_kernel<<<B_ / 32, 256, 0, stream>>>(x, label, xq, fws);
    tile_kernel<<<NBLK_, 512, 0, stream>>>(xq, x, label, fws, acc);
    finalize_kernel<<<1, 256, 0, stream>>>(fws, out);
}

// Round 8
// 98.655 us; speedup vs baseline: 1.3082x; 1.0670x over previous
//
#include <hip/hip_runtime.h>
#include <hip/hip_bf16.h>
#include <hip/hip_fp8.h>

#define B_ 8192
#define D_ 256
#define KS_ 64                               // certification subspace dims
#define EPS_ 1e-6f
#define MARGIN_ 1.0f
#define NT_ 64                               // 128-row tiles
#define NTILES_ (NT_ * (NT_ + 1) / 2)        // 2080
#define CEPS_ ((float)D_ * EPS_ * EPS_)
#define SCREEN_ 17.0f                        // d2_S screen: 1 + fp8 slack 16

typedef float floatx4 __attribute__((ext_vector_type(4)));

// ws layout: [0, 512KB) fp8 matrix (first 64 cols, stride 64 B);
// float region after 4 MB (offsets in floats)
#define XBF_BYTES (B_ * D_ * 2)
#define OFF_P      0        // pS[i]: partial ||x||^2 + 2 eps partial-sum (8192)
#define OFF_Q      8192     // qS[j]                                      (8192)
#define OFF_TP0    16384    // per-32-block full col sums, class 0 (256*256)
#define OFF_TP1    81920    // class 1                           (256*256)
#define OFF_PPP    147456   // per-block class sums of full p     (512)
#define OFF_QQP    147968   // per-block class sums of full q     (512)
#define OFF_CP     148480   // per-block count of class 0         (256)
#define OFF_PMINP  148736   // per-block min pS                   (256)
#define OFF_QMINP  148992   // per-block min qS                   (256)
#define OFF_ACC    149248   // hinge accumulator

__device__ __forceinline__ int trif(int t) { return (t * (129 - t)) / 2; }
__device__ __forceinline__ int decode_ti(int t) {
    int ti = (int)((129.0f - sqrtf(fmaxf(16641.0f - 8.0f * (float)t, 0.0f))) * 0.5f);
    ti = max(0, min(63, ti));
    while (trif(ti + 1) <= t) ++ti;
    while (trif(ti) > t) --ti;
    return ti;
}

// exact full-D hinge for a screened pair (expected ~never executed)
__device__ __noinline__ float exact_hinge(const float* __restrict__ x, int gi, int gj,
                                          const int* __restrict__ label) {
    if (label[gi] == label[gj]) return 0.0f;
    const float* xi = x + (size_t)gi * D_;
    const float* xj = x + (size_t)gj * D_;
    float sq = 0.0f;
    for (int k = 0; k < D_; ++k) {
        const float df = xi[k] - xj[k] + EPS_;
        sq += df * df;
    }
    if (sq < 1.0f) {
        const float d = sqrtf(fmaxf(sq, 1e-12f));
        const float h = MARGIN_ - d;
        return h * h;
    }
    return 0.0f;
}

// ---------------- prep: 256 blocks x 32 rows ----------------
__global__ __launch_bounds__(256) void prep_kernel(
    const float* __restrict__ x, const int* __restrict__ label,
    unsigned char* __restrict__ xqS, float* __restrict__ fws) {
    float* pS = fws + OFF_P;   float* qS = fws + OFF_Q;
    float* Tp0 = fws + OFF_TP0; float* Tp1 = fws + OFF_TP1;
    float* PpP = fws + OFF_PPP; float* QqP = fws + OFF_QQP;
    float* CpP = fws + OFF_CP;
    float* pminP = fws + OFF_PMINP; float* qminP = fws + OFF_QMINP;

    __shared__ int lab_s[32];
    __shared__ float spl[32], sql[32], spS[32], sqSl[32];
    __shared__ float colbuf0[4][256], colbuf1[4][256];

    const int blk = blockIdx.x;
    const int r0 = blk * 32;
    const int tid = threadIdx.x, w = tid >> 6, lane = tid & 63;

    if (tid < 32) lab_s[tid] = label[r0 + tid];
    __syncthreads();

    const float msk = (lane < 16) ? 1.0f : 0.0f;   // cols 0..63
    floatx4 t0 = (floatx4)0.0f, t1 = (floatx4)0.0f;
    #pragma unroll
    for (int i = 0; i < 8; ++i) {
        const int rloc = w * 8 + i;
        const int row = r0 + rloc;
        const floatx4 v = *(const floatx4*)(x + (size_t)row * D_ + lane * 4);
        float sq = v[0]*v[0] + v[1]*v[1] + v[2]*v[2] + v[3]*v[3];
        float rs = v[0] + v[1] + v[2] + v[3];
        float sqP = msk * sq, rsP = msk * rs;
        #pragma unroll
        for (int off = 32; off; off >>= 1) {
            sq  += __shfl_down(sq,  off);
            rs  += __shfl_down(rs,  off);
            sqP += __shfl_down(sqP, off);
            rsP += __shfl_down(rsP, off);
        }
        if (lane == 0) {
            spl[rloc]  = sq + 2.0f * EPS_ * rs;      // full p
            sql[rloc]  = sq - 2.0f * EPS_ * rs;      // full q
            const float pSv = sqP + 2.0f * EPS_ * rsP;
            const float qSv = sqP - 2.0f * EPS_ * rsP;
            pS[row] = pSv; qS[row] = qSv;
            spS[rloc] = pSv; sqSl[rloc] = qSv;
        }
        if (lab_s[rloc]) t1 += v; else t0 += v;      // wave-uniform branch
        if (lane < 16) {
            __hip_fp8_e4m3 c0(v[0]), c1(v[1]), c2(v[2]), c3(v[3]);
            const unsigned int u = (unsigned int)c0.__x | ((unsigned int)c1.__x << 8)
                                 | ((unsigned int)c2.__x << 16) | ((unsigned int)c3.__x << 24);
            *(unsigned int*)(xqS + (size_t)row * KS_ + lane * 4) = u;
        }
    }
    *(floatx4*)&colbuf0[w][lane * 4] = t0;
    *(floatx4*)&colbuf1[w][lane * 4] = t1;
    __syncthreads();

    {
        const int c = tid;
        Tp0[blk * 256 + c] = colbuf0[0][c] + colbuf0[1][c] + colbuf0[2][c] + colbuf0[3][c];
        Tp1[blk * 256 + c] = colbuf1[0][c] + colbuf1[1][c] + colbuf1[2][c] + colbuf1[3][c];
    }
    if (tid < 64) {
        const bool va = tid < 32;
        const float pv = va ? spl[tid & 31] : 0.0f;
        const float qv = va ? sql[tid & 31] : 0.0f;
        const int lb = va ? lab_s[tid & 31] : 0;
        float p0 = (va && !lb) ? pv : 0.0f, p1 = (va && lb) ? pv : 0.0f;
        float q0 = (va && !lb) ? qv : 0.0f, q1 = (va && lb) ? qv : 0.0f;
        float c0 = (va && !lb) ? 1.0f : 0.0f;
        float pm = va ? spS[tid & 31] : 1e30f;
        float qm = va ? sqSl[tid & 31] : 1e30f;
        #pragma unroll
        for (int off = 32; off; off >>= 1) {
            p0 += __shfl_down(p0, off); p1 += __shfl_down(p1, off);
            q0 += __shfl_down(q0, off); q1 += __shfl_down(q1, off);
            c0 += __shfl_down(c0, off);
            pm = fminf(pm, __shfl_down(pm, off));
            qm = fminf(qm, __shfl_down(qm, off));
        }
        if (tid == 0) {
            PpP[blk * 2 + 0] = p0; PpP[blk * 2 + 1] = p1;
            QqP[blk * 2 + 0] = q0; QqP[blk * 2 + 1] = q1;
            CpP[blk] = c0; pminP[blk] = pm; qminP[blk] = qm;
            if (blk == 0) fws[OFF_ACC] = 0.0f;
        }
    }
}

// ---------------- detect: K=64 fp8 gram, no LDS, no barriers ----------------
__global__ __launch_bounds__(256, 3) void detect_kernel(
    const unsigned char* __restrict__ xqS, const float* __restrict__ x,
    const int* __restrict__ label, const float* __restrict__ fws,
    float* __restrict__ acc) {
    const float* pS = fws + OFF_P;  const float* qS = fws + OFF_Q;
    const float* pminP = fws + OFF_PMINP; const float* qminP = fws + OFF_QMINP;

    const int ti = decode_ti(blockIdx.x);
    const int tj = ti + (blockIdx.x - trif(ti));
    const int i0 = ti * 128, j0 = tj * 128;

    const int tid = threadIdx.x, wave = tid >> 6, lane = tid & 63;
    const int quad = lane >> 4, r = lane & 15;
    const int wm = wave >> 1, wn = wave & 1;

    // A/B fragments straight from L2: row-major stride 64 B, frag = 8 B at k=ks*32+quad*8
    long av[8], bv[8];   // [mt*2+ks], [nt*2+ks]
    #pragma unroll
    for (int mt = 0; mt < 4; ++mt)
        #pragma unroll
        for (int ks = 0; ks < 2; ++ks) {
            av[mt * 2 + ks] = *(const long*)(xqS +
                (size_t)(i0 + wm * 64 + mt * 16 + r) * KS_ + ks * 32 + quad * 8);
            bv[mt * 2 + ks] = *(const long*)(xqS +
                (size_t)(j0 + wn * 64 + mt * 16 + r) * KS_ + ks * 32 + quad * 8);
        }

    floatx4 accv[16];
    #pragma unroll
    for (int t = 0; t < 16; ++t) accv[t] = (floatx4)0.0f;

    #pragma unroll
    for (int ks = 0; ks < 2; ++ks)
        #pragma unroll
        for (int mt = 0; mt < 4; ++mt)
            #pragma unroll
            for (int nt = 0; nt < 4; ++nt)
                accv[mt * 4 + nt] = __builtin_amdgcn_mfma_f32_16x16x32_fp8_fp8(
                    av[mt * 2 + ks], bv[nt * 2 + ks], accv[mt * 4 + nt], 0, 0, 0);

    // ---- detection ----
    float s = 0.0f;
    if (ti != tj) {
        float m = -1e30f;
        #pragma unroll
        for (int t = 0; t < 16; ++t)
            m = fmaxf(m, fmaxf(fmaxf(accv[t][0], accv[t][1]), fmaxf(accv[t][2], accv[t][3])));
        const float pmn = fminf(fminf(pminP[4 * ti], pminP[4 * ti + 1]),
                                fminf(pminP[4 * ti + 2], pminP[4 * ti + 3]));
        const float qmn = fminf(fminf(qminP[4 * tj], qminP[4 * tj + 1]),
                                fminf(qminP[4 * tj + 2], qminP[4 * tj + 3]));
        if (__any(2.0f * m > pmn + qmn - SCREEN_)) {
            // per-element screen (rare), then exact full-D fallback (~never)
            #pragma unroll
            for (int mt = 0; mt < 4; ++mt)
                #pragma unroll
                for (int nt = 0; nt < 4; ++nt)
                    #pragma unroll
                    for (int reg = 0; reg < 4; ++reg) {
                        const int gi = i0 + wm * 64 + mt * 16 + quad * 4 + reg;
                        const int gj = j0 + wn * 64 + nt * 16 + r;
                        const float sq8 = pS[gi] + qS[gj] - 2.0f * accv[mt * 4 + nt][reg];
                        if (sq8 < SCREEN_) s += exact_hinge(x, gi, gj, label);
                    }
        }
    } else {
        // diagonal: per-element screen with strict upper triangle
        #pragma unroll
        for (int mt = 0; mt < 4; ++mt)
            #pragma unroll
            for (int nt = 0; nt < 4; ++nt)
                #pragma unroll
                for (int reg = 0; reg < 4; ++reg) {
                    const int il = wm * 64 + mt * 16 + quad * 4 + reg;
                    const int jl = wn * 64 + nt * 16 + r;
                    if (il < jl) {
                        const int gi = i0 + il, gj = j0 + jl;
                        const float sq8 = pS[gi] + qS[gj] - 2.0f * accv[mt * 4 + nt][reg];
                        if (sq8 < SCREEN_) s += exact_hinge(x, gi, gj, label);
                    }
                }
    }
    #pragma unroll
    for (int off = 32; off; off >>= 1) s += __shfl_down(s, off);
    if (lane == 0 && s != 0.0f) atomicAdd(acc, s);
}

// ---------------- finalize: global analytic same-label sum ----------------
__global__ __launch_bounds__(256) void finalize_kernel(
    const float* __restrict__ fws, float* __restrict__ out) {
    const float* Tp0 = fws + OFF_TP0; const float* Tp1 = fws + OFF_TP1;
    const float* PpP = fws + OFF_PPP; const float* QqP = fws + OFF_QQP;
    const float* CpP = fws + OFF_CP;
    const float* acc = fws + OFF_ACC;

    __shared__ float buf[256];
    __shared__ double res[6];
    const int tid = threadIdx.x;

    // column sums of class col-sum vectors -> ||T0||^2 + ||T1||^2
    float S0 = 0.0f, S1 = 0.0f;
    for (int b = 0; b < 256; ++b) {
        S0 += Tp0[b * 256 + tid];
        S1 += Tp1[b * 256 + tid];
    }
    float vals[6];
    vals[0] = S0 * S0 + S1 * S1;
    vals[1] = PpP[2 * tid]; vals[2] = PpP[2 * tid + 1];
    vals[3] = QqP[2 * tid]; vals[4] = QqP[2 * tid + 1];
    vals[5] = CpP[tid];

    #pragma unroll
    for (int vi = 0; vi < 6; ++vi) {
        __syncthreads();
        buf[tid] = vals[vi];
        __syncthreads();
        if (tid < 64) {
            float a = buf[tid] + buf[tid + 64] + buf[tid + 128] + buf[tid + 192];
            #pragma unroll
            for (int off = 32; off; off >>= 1) a += __shfl_down(a, off);
            if (tid == 0) res[vi] = (double)a;
        }
    }
    __syncthreads();

    if (tid == 0) {
        const double Tsq = res[0];
        const double P0 = res[1], P1 = res[2], Q0 = res[3], Q1 = res[4];
        const double C0 = res[5], C1 = (double)B_ - C0;
        const double same = 0.5 * (C0 * (P0 + Q0) + C1 * (P1 + Q1)
                                 + (C0 * (C0 - 1.0) + C1 * (C1 - 1.0)) * (double)CEPS_
                                 - 2.0 * Tsq);
        const double total = same + (double)acc[0];
        const double cnt = (double)B_ * (double)(B_ - 1) / 2.0 + 1e-6;
        out[0] = (float)(total / cnt);
    }
}

extern "C" void kernel_launch(void* const* d_in, const int* in_sizes, int n_in,
                              void* d_out, int out_size, void* d_ws, size_t ws_size,
                              hipStream_t stream) {
    const float* x = (const float*)d_in[0];
    const int* label = (const int*)d_in[1];
    float* out = (float*)d_out;

    char* ws = (char*)d_ws;
    unsigned char* xqS = (unsigned char*)ws;
    float* fws = (float*)(ws + XBF_BYTES);
    float* acc = fws + OFF_ACC;

    prep_kernel<<<B_ / 32, 256, 0, stream>>>(x, label, xqS, fws);
    detect_kernel<<<NTILES_, 256, 0, stream>>>(xqS, x, label, fws, acc);
    finalize_kernel<<<1, 256, 0, stream>>>(fws, out);
}

// Round 9
// 97.238 us; speedup vs baseline: 1.3273x; 1.0146x over previous
//
#include <hip/hip_runtime.h>
#include <hip/hip_fp8.h>

#define B_ 8192
#define D_ 256
#define KS_ 64                               // certification subspace dims
#define EPS_ 1e-6f
#define MARGIN_ 1.0f
#define NT_ 64                               // 128-row tiles
#define NTILES_ (NT_ * (NT_ + 1) / 2)        // 2080
#define CEPS_ ((float)D_ * EPS_ * EPS_)
#define SCREEN_ 17.0f                        // d2_S screen: 1 + fp8 slack 16

typedef float floatx4 __attribute__((ext_vector_type(4)));

// ws layout: [0, 512KB) fp8 matrix (first 64 cols, stride 64 B);
// float region after 4 MB (offsets in floats)
#define XBF_BYTES (B_ * D_ * 2)
#define OFF_P    0        // pS[i] (subspace)                     (8192)
#define OFF_Q    8192     // qS[j]                                (8192)
#define OFF_S0   16384    // class-0 column sums (full 256 cols)  (256)
#define OFF_S1   16640    // class-1 column sums                  (256)
#define OFF_N0   16896    // sum ||x||^2 class 0
#define OFF_N1   16897    // class 1
#define OFF_C0   16898    // count class 0
#define OFF_ACC  16899    // hinge accumulator
#define ZERO_OFF 16384
#define ZERO_CNT 516

__device__ __forceinline__ int trif(int t) { return (t * (129 - t)) / 2; }
__device__ __forceinline__ int decode_ti(int t) {
    int ti = (int)((129.0f - sqrtf(fmaxf(16641.0f - 8.0f * (float)t, 0.0f))) * 0.5f);
    ti = max(0, min(63, ti));
    while (trif(ti + 1) <= t) ++ti;
    while (trif(ti) > t) --ti;
    return ti;
}

// exact full-D hinge for a screened pair (expected ~never executed)
__device__ __noinline__ float exact_hinge(const float* __restrict__ x, int gi, int gj,
                                          const int* __restrict__ label) {
    if (label[gi] == label[gj]) return 0.0f;
    const float* xi = x + (size_t)gi * D_;
    const float* xj = x + (size_t)gj * D_;
    float sq = 0.0f;
    for (int k = 0; k < D_; ++k) {
        const float df = xi[k] - xj[k] + EPS_;
        sq += df * df;
    }
    if (sq < 1.0f) {
        const float d = sqrtf(fmaxf(sq, 1e-12f));
        const float h = MARGIN_ - d;
        return h * h;
    }
    return 0.0f;
}

// ---------------- prep: 256 blocks x 32 rows ----------------
__global__ __launch_bounds__(256) void prep_kernel(
    const float* __restrict__ x, const int* __restrict__ label,
    unsigned char* __restrict__ xqS, float* __restrict__ fws) {
    float* pS = fws + OFF_P;   float* qS = fws + OFF_Q;

    __shared__ int lab_s[32];
    __shared__ float spn[32];                 // full ||x||^2 per row
    __shared__ float colbuf0[4][256], colbuf1[4][256];

    const int blk = blockIdx.x;
    const int r0 = blk * 32;
    const int tid = threadIdx.x, w = tid >> 6, lane = tid & 63;

    if (tid < 32) lab_s[tid] = label[r0 + tid];
    __syncthreads();

    floatx4 t0 = (floatx4)0.0f, t1 = (floatx4)0.0f;
    #pragma unroll
    for (int i = 0; i < 8; ++i) {
        const int rloc = w * 8 + i;
        const int row = r0 + rloc;
        const floatx4 v = *(const floatx4*)(x + (size_t)row * D_ + lane * 4);
        float sq = v[0]*v[0] + v[1]*v[1] + v[2]*v[2] + v[3]*v[3];
        float rs = v[0] + v[1] + v[2] + v[3];
        // reduce within 16-lane groups (lanes 0-15 hold cols 0-63 = subspace)
        #pragma unroll
        for (int off = 8; off; off >>= 1) {
            sq += __shfl_down(sq, off);
            rs += __shfl_down(rs, off);
        }
        const float sqS = sq, rsS = rs;       // lane 0: subspace sums
        sq += __shfl_down(sq, 16); rs += __shfl_down(rs, 16);
        sq += __shfl_down(sq, 32); rs += __shfl_down(rs, 32);
        if (lane == 0) {
            pS[row] = sqS + 2.0f * EPS_ * rsS;
            qS[row] = sqS - 2.0f * EPS_ * rsS;
            spn[rloc] = sq;                   // eps terms cancel in analytic same-sum
        }
        if (lab_s[rloc]) t1 += v; else t0 += v;   // wave-uniform branch
        if (lane < 16) {
            __hip_fp8_e4m3 c0(v[0]), c1(v[1]), c2(v[2]), c3(v[3]);
            const unsigned int u = (unsigned int)c0.__x | ((unsigned int)c1.__x << 8)
                                 | ((unsigned int)c2.__x << 16) | ((unsigned int)c3.__x << 24);
            *(unsigned int*)(xqS + (size_t)row * KS_ + lane * 4) = u;
        }
    }
    *(floatx4*)&colbuf0[w][lane * 4] = t0;
    *(floatx4*)&colbuf1[w][lane * 4] = t1;
    __syncthreads();

    // distributed column-sum reduction: one atomic per column per class
    atomicAdd(fws + OFF_S0 + tid,
              colbuf0[0][tid] + colbuf0[1][tid] + colbuf0[2][tid] + colbuf0[3][tid]);
    atomicAdd(fws + OFF_S1 + tid,
              colbuf1[0][tid] + colbuf1[1][tid] + colbuf1[2][tid] + colbuf1[3][tid]);

    // class scalars (first 32 lanes)
    if (tid < 32) {
        const float n = spn[tid];
        const int lb = lab_s[tid];
        float n0 = lb ? 0.0f : n, n1 = lb ? n : 0.0f;
        float c0 = lb ? 0.0f : 1.0f;
        #pragma unroll
        for (int off = 16; off; off >>= 1) {
            n0 += __shfl_down(n0, off);
            n1 += __shfl_down(n1, off);
            c0 += __shfl_down(c0, off);
        }
        if (tid == 0) {
            atomicAdd(fws + OFF_N0, n0);
            atomicAdd(fws + OFF_N1, n1);
            atomicAdd(fws + OFF_C0, c0);
        }
    }
}

// ---------------- detect: K=64 fp8 gram, no LDS, no barriers ----------------
__global__ __launch_bounds__(256, 3) void detect_kernel(
    const unsigned char* __restrict__ xqS, const float* __restrict__ x,
    const int* __restrict__ label, float* __restrict__ fws) {
    const float* pS = fws + OFF_P;  const float* qS = fws + OFF_Q;
    float* acc = fws + OFF_ACC;

    const int ti = decode_ti(blockIdx.x);
    const int tj = ti + (blockIdx.x - trif(ti));
    const int i0 = ti * 128, j0 = tj * 128;

    const int tid = threadIdx.x, wave = tid >> 6, lane = tid & 63;
    const int quad = lane >> 4, r = lane & 15;
    const int wm = wave >> 1, wn = wave & 1;

    // A/B fragments straight from L2: row-major stride 64 B, frag = 8 B at k=ks*32+quad*8
    long av[8], bv[8];   // [mt*2+ks], [nt*2+ks]
    #pragma unroll
    for (int mt = 0; mt < 4; ++mt)
        #pragma unroll
        for (int ks = 0; ks < 2; ++ks) {
            av[mt * 2 + ks] = *(const long*)(xqS +
                (size_t)(i0 + wm * 64 + mt * 16 + r) * KS_ + ks * 32 + quad * 8);
            bv[mt * 2 + ks] = *(const long*)(xqS +
                (size_t)(j0 + wn * 64 + mt * 16 + r) * KS_ + ks * 32 + quad * 8);
        }

    floatx4 accv[16];
    #pragma unroll
    for (int t = 0; t < 16; ++t) accv[t] = (floatx4)0.0f;

    #pragma unroll
    for (int ks = 0; ks < 2; ++ks)
        #pragma unroll
        for (int mt = 0; mt < 4; ++mt)
            #pragma unroll
            for (int nt = 0; nt < 4; ++nt)
                accv[mt * 4 + nt] = __builtin_amdgcn_mfma_f32_16x16x32_fp8_fp8(
                    av[mt * 2 + ks], bv[nt * 2 + ks], accv[mt * 4 + nt], 0, 0, 0);

    // ---- detection ----
    float s = 0.0f;
    if (ti != tj) {
        float m = -1e30f;
        #pragma unroll
        for (int t = 0; t < 16; ++t)
            m = fmaxf(m, fmaxf(fmaxf(accv[t][0], accv[t][1]), fmaxf(accv[t][2], accv[t][3])));
        // wave-local mins of pS over this wave's 64 i-rows / qS over 64 j-rows
        float pv = pS[i0 + wm * 64 + lane];
        float qv = qS[j0 + wn * 64 + lane];
        #pragma unroll
        for (int off = 32; off; off >>= 1) {
            pv = fminf(pv, __shfl_down(pv, off));
            qv = fminf(qv, __shfl_down(qv, off));
        }
        const float pmn = __shfl(pv, 0), qmn = __shfl(qv, 0);
        if (__any(2.0f * m > pmn + qmn - SCREEN_)) {
            // per-element screen (rare), then exact full-D fallback (~never)
            #pragma unroll
            for (int mt = 0; mt < 4; ++mt)
                #pragma unroll
                for (int nt = 0; nt < 4; ++nt)
                    #pragma unroll
                    for (int reg = 0; reg < 4; ++reg) {
                        const int gi = i0 + wm * 64 + mt * 16 + quad * 4 + reg;
                        const int gj = j0 + wn * 64 + nt * 16 + r;
                        const float sq8 = pS[gi] + qS[gj] - 2.0f * accv[mt * 4 + nt][reg];
                        if (sq8 < SCREEN_) s += exact_hinge(x, gi, gj, label);
                    }
        }
    } else {
        // diagonal: per-element screen with strict upper triangle
        #pragma unroll
        for (int mt = 0; mt < 4; ++mt)
            #pragma unroll
            for (int nt = 0; nt < 4; ++nt)
                #pragma unroll
                for (int reg = 0; reg < 4; ++reg) {
                    const int il = wm * 64 + mt * 16 + quad * 4 + reg;
                    const int jl = wn * 64 + nt * 16 + r;
                    if (il < jl) {
                        const int gi = i0 + il, gj = j0 + jl;
                        const float sq8 = pS[gi] + qS[gj] - 2.0f * accv[mt * 4 + nt][reg];
                        if (sq8 < SCREEN_) s += exact_hinge(x, gi, gj, label);
                    }
                }
    }
    #pragma unroll
    for (int off = 32; off; off >>= 1) s += __shfl_down(s, off);
    if (lane == 0 && s != 0.0f) atomicAdd(acc, s);
}

// ---------------- finalize: tiny analytic combine ----------------
__global__ __launch_bounds__(256) void finalize_kernel(
    const float* __restrict__ fws, float* __restrict__ out) {
    __shared__ float red[4];
    const int tid = threadIdx.x, w = tid >> 6, lane = tid & 63;

    const float a = fws[OFF_S0 + tid], b = fws[OFF_S1 + tid];
    float v = a * a + b * b;
    #pragma unroll
    for (int off = 32; off; off >>= 1) v += __shfl_down(v, off);
    if (lane == 0) red[w] = v;
    __syncthreads();

    if (tid == 0) {
        const double Tsq = (double)red[0] + (double)red[1] + (double)red[2] + (double)red[3];
        const double N0 = fws[OFF_N0], N1 = fws[OFF_N1];
        const double C0 = fws[OFF_C0], C1 = (double)B_ - C0;
        // sum_{i<j,same} d^2 = C0*N0 + C1*N1 - (||T0||^2+||T1||^2)
        //                    + [C0(C0-1)/2 + C1(C1-1)/2] * D*eps^2
        const double same = C0 * N0 + C1 * N1 - Tsq
                          + 0.5 * (C0 * (C0 - 1.0) + C1 * (C1 - 1.0)) * (double)CEPS_;
        const double total = same + (double)fws[OFF_ACC];
        const double cnt = (double)B_ * (double)(B_ - 1) / 2.0 + 1e-6;
        out[0] = (float)(total / cnt);
    }
}

extern "C" void kernel_launch(void* const* d_in, const int* in_sizes, int n_in,
                              void* d_out, int out_size, void* d_ws, size_t ws_size,
                              hipStream_t stream) {
    const float* x = (const float*)d_in[0];
    const int* label = (const int*)d_in[1];
    float* out = (float*)d_out;

    char* ws = (char*)d_ws;
    unsigned char* xqS = (unsigned char*)ws;
    float* fws = (float*)(ws + XBF_BYTES);

    hipMemsetAsync(fws + ZERO_OFF, 0, ZERO_CNT * sizeof(float), stream);
    prep_kernel<<<B_ / 32, 256, 0, stream>>>(x, label, xqS, fws);
    detect_kernel<<<NTILES_, 256, 0, stream>>>(xqS, x, label, fws);
    finalize_kernel<<<1, 256, 0, stream>>>(fws, out);
}

// Round 10
// 94.347 us; speedup vs baseline: 1.3680x; 1.0306x over previous
//
#include <hip/hip_runtime.h>
#include <hip/hip_fp8.h>

#define B_ 8192
#define D_ 256
#define KS_ 64                               // certification subspace dims
#define EPS_ 1e-6f
#define MARGIN_ 1.0f
#define NT_ 64                               // 128-row tiles
#define NTILES_ (NT_ * (NT_ + 1) / 2)        // 2080
#define CEPS_ ((float)D_ * EPS_ * EPS_)
#define SCREEN_ 17.0f                        // d2_S screen: 1 + fp8 slack 16

typedef float floatx4 __attribute__((ext_vector_type(4)));

// ws layout: [0, 512KB) fp8 fragment-packed matrix:
//   for row-group R (16 rows) and k-chunk ks (32 cols):
//   xqT[(R*2+ks)*512 + quad*128 + r*8 + b] = fp8(x[R*16+r][ks*32+quad*8+b])
// float region after 4 MB (offsets in floats)
#define XBF_BYTES (B_ * D_ * 2)
#define OFF_P    0        // pS[i] (subspace)                     (8192)
#define OFF_Q    8192     // qS[j]                                (8192)
#define OFF_S0   16384    // class-0 column sums (full 256 cols)  (256)
#define OFF_S1   16640    // class-1 column sums                  (256)
#define OFF_N0   16896    // sum ||x||^2 class 0
#define OFF_N1   16897    // class 1
#define OFF_C0   16898    // count class 0
#define OFF_ACC  16899    // hinge accumulator
#define ZERO_OFF 16384
#define ZERO_CNT 516

__device__ __forceinline__ int trif(int t) { return (t * (129 - t)) / 2; }
__device__ __forceinline__ int decode_ti(int t) {
    int ti = (int)((129.0f - sqrtf(fmaxf(16641.0f - 8.0f * (float)t, 0.0f))) * 0.5f);
    ti = max(0, min(63, ti));
    while (trif(ti + 1) <= t) ++ti;
    while (trif(ti) > t) --ti;
    return ti;
}

// exact full-D hinge for a screened pair (expected ~never executed)
__device__ __noinline__ float exact_hinge(const float* __restrict__ x, int gi, int gj,
                                          const int* __restrict__ label) {
    if (label[gi] == label[gj]) return 0.0f;
    const float* xi = x + (size_t)gi * D_;
    const float* xj = x + (size_t)gj * D_;
    float sq = 0.0f;
    for (int k = 0; k < D_; ++k) {
        const float df = xi[k] - xj[k] + EPS_;
        sq += df * df;
    }
    if (sq < 1.0f) {
        const float d = sqrtf(fmaxf(sq, 1e-12f));
        const float h = MARGIN_ - d;
        return h * h;
    }
    return 0.0f;
}

// ---------------- prep: 256 blocks x 32 rows ----------------
__global__ __launch_bounds__(256) void prep_kernel(
    const float* __restrict__ x, const int* __restrict__ label,
    unsigned char* __restrict__ xqT, float* __restrict__ fws) {
    float* pS = fws + OFF_P;   float* qS = fws + OFF_Q;

    __shared__ int lab_s[32];
    __shared__ float spn[32];                 // full ||x||^2 per row
    __shared__ float colbuf0[4][256], colbuf1[4][256];

    const int blk = blockIdx.x;
    const int r0 = blk * 32;
    const int tid = threadIdx.x, w = tid >> 6, lane = tid & 63;

    if (tid < 32) lab_s[tid] = label[r0 + tid];
    __syncthreads();

    floatx4 t0 = (floatx4)0.0f, t1 = (floatx4)0.0f;
    #pragma unroll
    for (int i = 0; i < 8; ++i) {
        const int rloc = w * 8 + i;
        const int row = r0 + rloc;
        const floatx4 v = *(const floatx4*)(x + (size_t)row * D_ + lane * 4);
        float sq = v[0]*v[0] + v[1]*v[1] + v[2]*v[2] + v[3]*v[3];
        float rs = v[0] + v[1] + v[2] + v[3];
        // reduce within 16-lane groups (lanes 0-15 hold cols 0-63 = subspace)
        #pragma unroll
        for (int off = 8; off; off >>= 1) {
            sq += __shfl_down(sq, off);
            rs += __shfl_down(rs, off);
        }
        const float sqS = sq, rsS = rs;       // lane 0: subspace sums
        sq += __shfl_down(sq, 16); rs += __shfl_down(rs, 16);
        sq += __shfl_down(sq, 32); rs += __shfl_down(rs, 32);
        if (lane == 0) {
            pS[row] = sqS + 2.0f * EPS_ * rsS;
            qS[row] = sqS - 2.0f * EPS_ * rsS;
            spn[rloc] = sq;                   // eps terms cancel in analytic same-sum
        }
        if (lab_s[rloc]) t1 += v; else t0 += v;   // wave-uniform branch
        if (lane < 16) {
            __hip_fp8_e4m3 c0(v[0]), c1(v[1]), c2(v[2]), c3(v[3]);
            const unsigned int u = (unsigned int)c0.__x | ((unsigned int)c1.__x << 8)
                                 | ((unsigned int)c2.__x << 16) | ((unsigned int)c3.__x << 24);
            // fragment-packed store: cols 4*lane..4*lane+3 of `row`
            const int R = row >> 4, r = row & 15;
            const int ks = lane >> 3, quad = (lane >> 1) & 3, b = (lane & 1) * 4;
            *(unsigned int*)(xqT + (((R * 2 + ks) << 9) | (quad << 7) | (r << 3) | b)) = u;
        }
    }
    *(floatx4*)&colbuf0[w][lane * 4] = t0;
    *(floatx4*)&colbuf1[w][lane * 4] = t1;
    __syncthreads();

    // distributed column-sum reduction: one atomic per column per class
    atomicAdd(fws + OFF_S0 + tid,
              colbuf0[0][tid] + colbuf0[1][tid] + colbuf0[2][tid] + colbuf0[3][tid]);
    atomicAdd(fws + OFF_S1 + tid,
              colbuf1[0][tid] + colbuf1[1][tid] + colbuf1[2][tid] + colbuf1[3][tid]);

    // class scalars (first 32 lanes)
    if (tid < 32) {
        const float n = spn[tid];
        const int lb = lab_s[tid];
        float n0 = lb ? 0.0f : n, n1 = lb ? n : 0.0f;
        float c0 = lb ? 0.0f : 1.0f;
        #pragma unroll
        for (int off = 16; off; off >>= 1) {
            n0 += __shfl_down(n0, off);
            n1 += __shfl_down(n1, off);
            c0 += __shfl_down(c0, off);
        }
        if (tid == 0) {
            atomicAdd(fws + OFF_N0, n0);
            atomicAdd(fws + OFF_N1, n1);
            atomicAdd(fws + OFF_C0, c0);
        }
    }
}

// ---------------- detect: K=64 fp8 gram, coalesced fragment loads ----------------
__global__ __launch_bounds__(256, 3) void detect_kernel(
    const unsigned char* __restrict__ xqT, const float* __restrict__ x,
    const int* __restrict__ label, float* __restrict__ fws) {
    const float* pS = fws + OFF_P;  const float* qS = fws + OFF_Q;
    float* acc = fws + OFF_ACC;

    const int ti = decode_ti(blockIdx.x);
    const int tj = ti + (blockIdx.x - trif(ti));
    const int i0 = ti * 128, j0 = tj * 128;

    const int tid = threadIdx.x, wave = tid >> 6, lane = tid & 63;
    const int quad = lane >> 4, r = lane & 15;
    const int wm = wave >> 1, wn = wave & 1;

    // fragment loads: per (mt,ks) one fully-contiguous 512-B wave segment
    // addr = (R*2+ks)*512 + quad*128 + r*8 = base + lane*8
    const int Ri = (i0 >> 4) + wm * 4;       // row-group base for A
    const int Rj = (j0 >> 4) + wn * 4;       // row-group base for B
    const int lo = (quad << 7) | (r << 3);   // = lane*8
    long av[8], bv[8];   // [mt*2+ks]
    #pragma unroll
    for (int mt = 0; mt < 4; ++mt)
        #pragma unroll
        for (int ks = 0; ks < 2; ++ks) {
            av[mt * 2 + ks] = *(const long*)(xqT + ((((Ri + mt) * 2 + ks) << 9) | lo));
            bv[mt * 2 + ks] = *(const long*)(xqT + ((((Rj + mt) * 2 + ks) << 9) | lo));
        }

    floatx4 accv[16];
    #pragma unroll
    for (int t = 0; t < 16; ++t) accv[t] = (floatx4)0.0f;

    #pragma unroll
    for (int ks = 0; ks < 2; ++ks)
        #pragma unroll
        for (int mt = 0; mt < 4; ++mt)
            #pragma unroll
            for (int nt = 0; nt < 4; ++nt)
                accv[mt * 4 + nt] = __builtin_amdgcn_mfma_f32_16x16x32_fp8_fp8(
                    av[mt * 2 + ks], bv[nt * 2 + ks], accv[mt * 4 + nt], 0, 0, 0);

    // ---- detection ----
    float s = 0.0f;
    if (ti != tj) {
        float m = -1e30f;
        #pragma unroll
        for (int t = 0; t < 16; ++t)
            m = fmaxf(m, fmaxf(fmaxf(accv[t][0], accv[t][1]), fmaxf(accv[t][2], accv[t][3])));
        // wave-local mins of pS over this wave's 64 i-rows / qS over 64 j-rows
        float pv = pS[i0 + wm * 64 + lane];
        float qv = qS[j0 + wn * 64 + lane];
        #pragma unroll
        for (int off = 32; off; off >>= 1) {
            pv = fminf(pv, __shfl_down(pv, off));
            qv = fminf(qv, __shfl_down(qv, off));
        }
        const float pmn = __shfl(pv, 0), qmn = __shfl(qv, 0);
        if (__any(2.0f * m > pmn + qmn - SCREEN_)) {
            // per-element screen (rare), then exact full-D fallback (~never)
            #pragma unroll
            for (int mt = 0; mt < 4; ++mt)
                #pragma unroll
                for (int nt = 0; nt < 4; ++nt)
                    #pragma unroll
                    for (int reg = 0; reg < 4; ++reg) {
                        const int gi = i0 + wm * 64 + mt * 16 + quad * 4 + reg;
                        const int gj = j0 + wn * 64 + nt * 16 + r;
                        const float sq8 = pS[gi] + qS[gj] - 2.0f * accv[mt * 4 + nt][reg];
                        if (sq8 < SCREEN_) s += exact_hinge(x, gi, gj, label);
                    }
        }
    } else {
        // diagonal: per-element screen with strict upper triangle
        #pragma unroll
        for (int mt = 0; mt < 4; ++mt)
            #pragma unroll
            for (int nt = 0; nt < 4; ++nt)
                #pragma unroll
                for (int reg = 0; reg < 4; ++reg) {
                    const int il = wm * 64 + mt * 16 + quad * 4 + reg;
                    const int jl = wn * 64 + nt * 16 + r;
                    if (il < jl) {
                        const int gi = i0 + il, gj = j0 + jl;
                        const float sq8 = pS[gi] + qS[gj] - 2.0f * accv[mt * 4 + nt][reg];
                        if (sq8 < SCREEN_) s += exact_hinge(x, gi, gj, label);
                    }
                }
    }
    #pragma unroll
    for (int off = 32; off; off >>= 1) s += __shfl_down(s, off);
    if (lane == 0 && s != 0.0f) atomicAdd(acc, s);
}

// ---------------- finalize: tiny analytic combine ----------------
__global__ __launch_bounds__(256) void finalize_kernel(
    const float* __restrict__ fws, float* __restrict__ out) {
    __shared__ float red[4];
    const int tid = threadIdx.x, w = tid >> 6, lane = tid & 63;

    const float a = fws[OFF_S0 + tid], b = fws[OFF_S1 + tid];
    float v = a * a + b * b;
    #pragma unroll
    for (int off = 32; off; off >>= 1) v += __shfl_down(v, off);
    if (lane == 0) red[w] = v;
    __syncthreads();

    if (tid == 0) {
        const double Tsq = (double)red[0] + (double)red[1] + (double)red[2] + (double)red[3];
        const double N0 = fws[OFF_N0], N1 = fws[OFF_N1];
        const double C0 = fws[OFF_C0], C1 = (double)B_ - C0;
        // sum_{i<j,same} d^2 = C0*N0 + C1*N1 - (||T0||^2+||T1||^2)
        //                    + [C0(C0-1)/2 + C1(C1-1)/2] * D*eps^2
        const double same = C0 * N0 + C1 * N1 - Tsq
                          + 0.5 * (C0 * (C0 - 1.0) + C1 * (C1 - 1.0)) * (double)CEPS_;
        const double total = same + (double)fws[OFF_ACC];
        const double cnt = (double)B_ * (double)(B_ - 1) / 2.0 + 1e-6;
        out[0] = (float)(total / cnt);
    }
}

extern "C" void kernel_launch(void* const* d_in, const int* in_sizes, int n_in,
                              void* d_out, int out_size, void* d_ws, size_t ws_size,
                              hipStream_t stream) {
    const float* x = (const float*)d_in[0];
    const int* label = (const int*)d_in[1];
    float* out = (float*)d_out;

    char* ws = (char*)d_ws;
    unsigned char* xqT = (unsigned char*)ws;
    float* fws = (float*)(ws + XBF_BYTES);

    hipMemsetAsync(fws + ZERO_OFF, 0, ZERO_CNT * sizeof(float), stream);
    prep_kernel<<<B_ / 32, 256, 0, stream>>>(x, label, xqT, fws);
    detect_kernel<<<NTILES_, 256, 0, stream>>>(xqT, x, label, fws);
    finalize_kernel<<<1, 256, 0, stream>>>(fws, out);
}